// Round 4
// baseline (1397.127 us; speedup 1.0000x reference)
//
#include <hip/hip_runtime.h>

// Char-LSTM (B=4096, T=40, H=256, V=128) on MI355X — weight-stationary v2.
//
// Round-3 post-mortem: single-counter grid barrier (256 serialized atomic RMWs
// ~12us/step) + post-invalidate L3 refetch latency dominated => 1011us.
// Round-4 changes:
//  1. Flag-tree barrier: per-block padded arrival flags + leader release of a
//     generation word. No RMW contention.
//  2. Partition mapping cs=bid>>5, rg=bid&31: the 8 col-slices sharing the same
//     128 h rows land on one XCD (bid%8==rg%8) -> h read amplification served
//     by XCD L2, L3 h traffic 32MB->4MB/step.
//  3. Emb gathers for step t+1 prefetched into registers BEFORE the barrier
//     (Emb is constant -> cache staleness irrelevant); off the critical path.
// Numerics identical to rounds 2/3 (3-pass split bf16, absmax 4.88e-4).

#define SEQ     40
#define VCH     128
#define HID     256
#define GATES   1024
#define NBLK    256
#define THREADS 512

typedef __attribute__((ext_vector_type(8))) short short8;   // 8 bf16
typedef __attribute__((ext_vector_type(4))) float f32x4;
typedef __attribute__((ext_vector_type(4))) unsigned int uint4v;

#define MFMA16(a, b, c) __builtin_amdgcn_mfma_f32_16x16x32_bf16((a), (b), (c), 0, 0, 0)

__device__ __forceinline__ unsigned short f2bf(float x) {
    unsigned u = __float_as_uint(x);
    return (unsigned short)((u + 0x7FFFu + ((u >> 16) & 1u)) >> 16);   // RNE
}
__device__ __forceinline__ float bf2f(unsigned short b) {
    return __uint_as_float(((unsigned)b) << 16);
}
__device__ __forceinline__ float sigm(float x) {
    return 1.0f / (1.0f + __expf(-x));
}
__device__ __forceinline__ float tanh_fast(float x) {
    float e = __expf(2.0f * x);
    return 1.0f - 2.0f / (e + 1.0f);
}

// ---------------------------------------------------------------------------
// ws layout (bytes):
//   Whi   ushort[262144] @ 0        (512 KB)
//   Wlo   ushort[262144] @ 512K     (512 KB)
//   Wdhi  ushort[32768]  @ 1024K    ( 64 KB)
//   Wdlo  ushort[32768]  @ 1088K    ( 64 KB)
//   Emb   float[131072]  @ 1152K    (512 KB)  Emb[ch][pcol] = W_x[ch,oc]+b[oc]
//   hbuf  uint[2][4096*256] @ 1664K (8 MB)    ping-pong packed h (hi16|lo16)
//   barz  int[8224]      @ 10092544 (~33 KB)  [0]=generation, [32+b*32]=flag b
// ---------------------------------------------------------------------------

__global__ void pack_all(const float* __restrict__ W_lstm,
                         const float* __restrict__ b_lstm,
                         const float* __restrict__ W_dense,
                         unsigned short* __restrict__ Whi,
                         unsigned short* __restrict__ Wlo,
                         unsigned short* __restrict__ Wdhi,
                         unsigned short* __restrict__ Wdlo,
                         float* __restrict__ Emb,
                         int* __restrict__ barz) {
    int idx = blockIdx.x * blockDim.x + threadIdx.x;
    if (idx < 8224) barz[idx] = 0;
    if (idx < 262144) {
        // idx = (((cs*8+f)*8+kc)*64+lane)*8+j
        int j = idx & 7, lane = (idx >> 3) & 63, kc = (idx >> 9) & 7;
        int f = (idx >> 12) & 7, cs = idx >> 15;
        int oc = (f & 3) * 256 + cs * 32 + (f >> 2) * 16 + (lane & 15);
        int k  = kc * 32 + (lane >> 4) * 8 + j;
        float w = W_lstm[(size_t)(VCH + k) * GATES + oc];
        unsigned short hi = f2bf(w);
        Whi[idx] = hi;
        Wlo[idx] = f2bf(w - bf2f(hi));
    } else if (idx < 262144 + 32768) {
        int i2 = idx - 262144;
        int j = i2 & 7, lane = (i2 >> 3) & 63, kc = (i2 >> 9) & 7, f = i2 >> 12;
        int col = f * 16 + (lane & 15);
        int k   = kc * 32 + (lane >> 4) * 8 + j;
        float w = W_dense[(size_t)k * VCH + col];
        unsigned short hi = f2bf(w);
        Wdhi[i2] = hi;
        Wdlo[i2] = f2bf(w - bf2f(hi));
    } else if (idx < 262144 + 32768 + 131072) {
        int i3 = idx - (262144 + 32768);
        int pcol = i3 & 1023, ch = i3 >> 10;
        int cs = pcol >> 7, f = (pcol >> 4) & 7, n = pcol & 15;
        int oc = (f & 3) * 256 + cs * 32 + (f >> 2) * 16 + n;
        Emb[i3] = W_lstm[(size_t)ch * GATES + oc] + b_lstm[oc];
    }
}

// Flag-tree grid barrier. want = 1-based barrier index (monotonic).
// Release/acquire at agent scope: arrival release publishes the block's h
// stores; observing acquire emits buffer_inv (L1+L2) AFTER the observing load,
// so post-barrier loads see fresh data. Leader chain is transitive.
__device__ __forceinline__ void gridbar(int* __restrict__ barz, int want) {
    __syncthreads();   // all waves drain vmem (compiler emits vmcnt(0))
    if (blockIdx.x == 0) {
        int t = threadIdx.x;
        if (t > 0 && t < NBLK) {
            while (__hip_atomic_load(&barz[32 + t * 32], __ATOMIC_ACQUIRE,
                                     __HIP_MEMORY_SCOPE_AGENT) < want)
                __builtin_amdgcn_s_sleep(1);
        }
        __syncthreads();
        if (t == 0)
            __hip_atomic_store(&barz[0], want, __ATOMIC_RELEASE,
                               __HIP_MEMORY_SCOPE_AGENT);
        __syncthreads();
    } else {
        if (threadIdx.x == 0) {
            __hip_atomic_store(&barz[32 + blockIdx.x * 32], want, __ATOMIC_RELEASE,
                               __HIP_MEMORY_SCOPE_AGENT);
            while (__hip_atomic_load(&barz[0], __ATOMIC_ACQUIRE,
                                     __HIP_MEMORY_SCOPE_AGENT) < want)
                __builtin_amdgcn_s_sleep(1);
        }
        __syncthreads();
    }
}

__device__ __forceinline__ void unpack_a(uint4v u0, uint4v u1, short8& hi, short8& lo) {
    union { uint4v u; short8 s; } ch, cl;
    ch.u = (uint4v){ (u0[0] >> 16) | (u0[1] & 0xFFFF0000u),
                     (u0[2] >> 16) | (u0[3] & 0xFFFF0000u),
                     (u1[0] >> 16) | (u1[1] & 0xFFFF0000u),
                     (u1[2] >> 16) | (u1[3] & 0xFFFF0000u) };
    cl.u = (uint4v){ (u0[0] & 0xFFFFu) | (u0[1] << 16),
                     (u0[2] & 0xFFFFu) | (u0[3] << 16),
                     (u1[0] & 0xFFFFu) | (u1[1] << 16),
                     (u1[2] & 0xFFFFu) | (u1[3] << 16) };
    hi = ch.s;
    lo = cl.s;
}

__global__ __launch_bounds__(THREADS, 2)
void lstm_main(const int* __restrict__ inputs,
               const unsigned short* __restrict__ Whi,
               const unsigned short* __restrict__ Wlo,
               const unsigned short* __restrict__ Wdhi,
               const unsigned short* __restrict__ Wdlo,
               const float* __restrict__ Emb,
               const float* __restrict__ b_dense,
               unsigned int* __restrict__ hbuf,
               int* __restrict__ barz,
               float* __restrict__ out) {
    __shared__ __align__(16) unsigned short wsh[32768];   // 64 KB
    __shared__ __align__(16) unsigned short wsl[32768];   // 64 KB
    __shared__ int chs[SEQ * 128];                        // 20 KB

    const int tid  = threadIdx.x;
    const int lane = tid & 63;
    const int w    = tid >> 6;
    const int n    = lane & 15;
    const int kq   = lane >> 4;
    // XCD-friendly mapping: all 8 cs of one rg land on the same XCD (bid%8==rg%8)
    const int cs   = blockIdx.x >> 5;      // col-slice 0..7
    const int rg   = blockIdx.x & 31;      // row-group 0..31
    const int r0   = rg * 128;
    const int rw   = r0 + w * 16;

    // ---- stage weight slice into LDS (one-time) ---------------------------
    {
        const uint4v* gh = (const uint4v*)(Whi + (size_t)cs * 32768);
        const uint4v* gl = (const uint4v*)(Wlo + (size_t)cs * 32768);
        uint4v* lh = (uint4v*)wsh;
        uint4v* ll = (uint4v*)wsl;
        for (int i = tid; i < 4096; i += THREADS) { lh[i] = gh[i]; ll[i] = gl[i]; }
    }
    for (int i = tid; i < SEQ * 128; i += THREADS) {
        int row = i & 127, t = i >> 7;
        chs[t * 128 + row] = inputs[(size_t)(r0 + row) * SEQ + t];
    }
    for (int i = tid; i < 128 * 32; i += THREADS) {
        int rr = i >> 5, cc = i & 31;
        __hip_atomic_store(&hbuf[(size_t)(r0 + rr) * HID + cs * 32 + cc], 0u,
                           __ATOMIC_RELAXED, __HIP_MEMORY_SCOPE_AGENT);
    }

    float c_st[8];
#pragma unroll
    for (int i = 0; i < 8; ++i) c_st[i] = 0.0f;

    int gen = 1;
    gridbar(barz, gen); gen++;   // hbuf[0] zeros visible; LDS staged

    const float* embbase = Emb + cs * 128 + n;

    // preload embedding gather for t=0
    float gv[8][4];
    {
        int ch[4];
#pragma unroll
        for (int r = 0; r < 4; ++r) ch[r] = chs[w * 16 + kq * 4 + r];
#pragma unroll
        for (int f = 0; f < 8; ++f)
#pragma unroll
            for (int r = 0; r < 4; ++r)
                gv[f][r] = embbase[(size_t)ch[r] * GATES + f * 16];
    }

#pragma unroll 1
    for (int t = 0; t < SEQ; ++t) {
        const unsigned int* hb = hbuf + (size_t)(t & 1) * 4096 * HID;
        unsigned int* hw = hbuf + (size_t)((t & 1) ^ 1) * 4096 * HID;

        // ---- A loads: this wave's 16 rows, packed u32, vectorized ---------
        const unsigned int* arow = hb + (size_t)(rw + n) * HID + kq * 8;
        uint4v araw[16];
#pragma unroll
        for (int kc = 0; kc < 8; ++kc) {
            araw[kc * 2]     = *(const uint4v*)(arow + kc * 32);
            araw[kc * 2 + 1] = *(const uint4v*)(arow + kc * 32 + 4);
        }

        // ---- 3-pass MFMA: z = h @ W_slice ---------------------------------
        f32x4 acc[8];
#pragma unroll
        for (int f = 0; f < 8; ++f) acc[f] = (f32x4){0.f, 0.f, 0.f, 0.f};
#pragma unroll
        for (int kc = 0; kc < 8; ++kc) {
            short8 ahi, alo;
            unpack_a(araw[kc * 2], araw[kc * 2 + 1], ahi, alo);
#pragma unroll
            for (int f = 0; f < 8; ++f) {
                short8 bh = *(const short8*)&wsh[(f * 8 + kc) * 512 + lane * 8];
                short8 bl = *(const short8*)&wsl[(f * 8 + kc) * 512 + lane * 8];
                acc[f] = MFMA16(ahi, bh, acc[f]);
                acc[f] = MFMA16(alo, bh, acc[f]);
                acc[f] = MFMA16(ahi, bl, acc[f]);
            }
        }

        // ---- in-register cell update; publish h ---------------------------
#pragma unroll
        for (int hf = 0; hf < 2; ++hf) {
#pragma unroll
            for (int r = 0; r < 4; ++r) {
                float zi = acc[hf * 4 + 0][r] + gv[hf * 4 + 0][r];
                float zj = acc[hf * 4 + 1][r] + gv[hf * 4 + 1][r];
                float zf = acc[hf * 4 + 2][r] + gv[hf * 4 + 2][r];
                float zo = acc[hf * 4 + 3][r] + gv[hf * 4 + 3][r];
                float cc = sigm(zf + 1.0f) * c_st[hf * 4 + r]
                         + sigm(zi) * tanh_fast(zj);
                c_st[hf * 4 + r] = cc;
                float hh = sigm(zo) * tanh_fast(cc);
                unsigned short hi = f2bf(hh);
                unsigned short lo = f2bf(hh - bf2f(hi));
                unsigned int pk = ((unsigned int)hi << 16) | (unsigned int)lo;
                __hip_atomic_store(&hw[(size_t)(rw + kq * 4 + r) * HID + cs * 32 + hf * 16 + n],
                                   pk, __ATOMIC_RELAXED, __HIP_MEMORY_SCOPE_AGENT);
            }
        }

        // ---- prefetch next step's embedding gather (constant data, safe
        //      to read pre-barrier; values live in registers across the inv)
        if (t + 1 < SEQ) {
            int ch[4];
#pragma unroll
            for (int r = 0; r < 4; ++r) ch[r] = chs[(t + 1) * 128 + w * 16 + kq * 4 + r];
#pragma unroll
            for (int f = 0; f < 8; ++f)
#pragma unroll
                for (int r = 0; r < 4; ++r)
                    gv[f][r] = embbase[(size_t)ch[r] * GATES + f * 16];
        }

        gridbar(barz, gen); gen++;
    }

    // ---- final dense: out[:, cs*16..+16] = h @ Wd + b ---------------------
    {
        const unsigned int* hb = hbuf;   // t=39 wrote buf[0]
        const unsigned int* arow = hb + (size_t)(rw + n) * HID + kq * 8;
        f32x4 dacc = (f32x4){0.f, 0.f, 0.f, 0.f};
#pragma unroll
        for (int kc = 0; kc < 8; ++kc) {
            uint4v u0 = *(const uint4v*)(arow + kc * 32);
            uint4v u1 = *(const uint4v*)(arow + kc * 32 + 4);
            short8 ahi, alo;
            unpack_a(u0, u1, ahi, alo);
            short8 bh = *(const short8*)(Wdhi + (size_t)(cs * 8 + kc) * 512 + lane * 8);
            short8 bl = *(const short8*)(Wdlo + (size_t)(cs * 8 + kc) * 512 + lane * 8);
            dacc = MFMA16(ahi, bh, dacc);
            dacc = MFMA16(alo, bh, dacc);
            dacc = MFMA16(ahi, bl, dacc);
        }
        float bd = b_dense[cs * 16 + n];
#pragma unroll
        for (int r = 0; r < 4; ++r) {
            out[(size_t)(rw + kq * 4 + r) * VCH + cs * 16 + n] = dacc[r] + bd;
        }
    }
}

extern "C" void kernel_launch(void* const* d_in, const int* in_sizes, int n_in,
                              void* d_out, int out_size, void* d_ws, size_t ws_size,
                              hipStream_t stream) {
    const int*   inputs  = (const int*)d_in[0];
    const float* W_lstm  = (const float*)d_in[1];
    const float* b_lstm  = (const float*)d_in[2];
    const float* W_dense = (const float*)d_in[3];
    const float* b_dense = (const float*)d_in[4];
    float* out = (float*)d_out;

    char* ws = (char*)d_ws;
    unsigned short* Whi  = (unsigned short*)(ws);
    unsigned short* Wlo  = (unsigned short*)(ws + 524288);
    unsigned short* Wdhi = (unsigned short*)(ws + 1048576);
    unsigned short* Wdlo = (unsigned short*)(ws + 1114112);
    float*          Emb  = (float*)(ws + 1179648);
    unsigned int*   hbuf = (unsigned int*)(ws + 1703936);
    int*            barz = (int*)(ws + 1703936 + 8388608);

    const int total = 262144 + 32768 + 131072;
    hipLaunchKernelGGL(pack_all, dim3((total + 255) / 256), dim3(256), 0, stream,
                       W_lstm, b_lstm, W_dense, Whi, Wlo, Wdhi, Wdlo, Emb, barz);

    void* args[] = { (void*)&inputs, (void*)&Whi, (void*)&Wlo, (void*)&Wdhi,
                     (void*)&Wdlo, (void*)&Emb, (void*)&b_dense, (void*)&hbuf,
                     (void*)&barz, (void*)&out };
    hipError_t err = hipLaunchCooperativeKernel((const void*)lstm_main, dim3(NBLK),
                                                dim3(THREADS), args, 0, stream);
    if (err != hipSuccess) {
        hipLaunchKernelGGL(lstm_main, dim3(NBLK), dim3(THREADS), 0, stream,
                           inputs, Whi, Wlo, Wdhi, Wdlo, Emb, b_dense, hbuf, barz, out);
    }
}

// Round 5
// 614.008 us; speedup vs baseline: 2.2754x; 2.2754x over previous
//
#include <hip/hip_runtime.h>

// Char-LSTM (B=4096, T=40, H=256, V=128) on MI355X — weight-stationary v3.
//
// R3/R4 post-mortem: ACQUIRE-poll spin loops emit buffer_inv per iteration
// (L1+L2 wipe, agent scope) -> chip-wide invalidate storm ~20-30us/step.
// R5: zero-invalidate design.
//   * hbuf is exchanged ONLY through sc1 (cache-bypassing) accesses:
//     stores = relaxed agent atomics (as before), loads = inline-asm
//     global_load_dwordx4 sc1. L1/L2 never hold hbuf lines -> barrier needs
//     no invalidate; Emb/W/chs stay cached across all 40 steps.
//   * Barrier polls are RELAXED (sc1 load, no inv). Release ordering is free:
//     __syncthreads drains vmcnt(0) per wave before s_barrier; arrival flag
//     uses one RELEASE store.
// Numerics identical to R2-R4 (3-pass split bf16, absmax 4.88e-4).

#define SEQ     40
#define VCH     128
#define HID     256
#define GATES   1024
#define NBLK    256
#define THREADS 512

typedef __attribute__((ext_vector_type(8))) short short8;   // 8 bf16
typedef __attribute__((ext_vector_type(4))) float f32x4;
typedef __attribute__((ext_vector_type(4))) unsigned int uint4v;

#define MFMA16(a, b, c) __builtin_amdgcn_mfma_f32_16x16x32_bf16((a), (b), (c), 0, 0, 0)

__device__ __forceinline__ unsigned short f2bf(float x) {
    unsigned u = __float_as_uint(x);
    return (unsigned short)((u + 0x7FFFu + ((u >> 16) & 1u)) >> 16);   // RNE
}
__device__ __forceinline__ float bf2f(unsigned short b) {
    return __uint_as_float(((unsigned)b) << 16);
}
__device__ __forceinline__ float sigm(float x) {
    return 1.0f / (1.0f + __expf(-x));
}
__device__ __forceinline__ float tanh_fast(float x) {
    float e = __expf(2.0f * x);
    return 1.0f - 2.0f / (e + 1.0f);
}

// 16B load that bypasses L1/L2 (sc1): sees agent-coherent (L3) data without
// any cache invalidate. NOTE: result is NOT valid until s_waitcnt vmcnt(0) +
// sched_barrier(0) (issued once after the batch of loads).
__device__ __forceinline__ uint4v ld16_sc1(const unsigned int* p) {
    uint4v r;
    asm volatile("global_load_dwordx4 %0, %1, off sc1"
                 : "=&v"(r) : "v"(p) : "memory");
    return r;
}
__device__ __forceinline__ void vm_drain() {
    asm volatile("s_waitcnt vmcnt(0)" ::: "memory");
    __builtin_amdgcn_sched_barrier(0);
}

// ---------------------------------------------------------------------------
// ws layout (bytes):
//   Whi   ushort[262144] @ 0        (512 KB)
//   Wlo   ushort[262144] @ 512K     (512 KB)
//   Wdhi  ushort[32768]  @ 1024K    ( 64 KB)
//   Wdlo  ushort[32768]  @ 1088K    ( 64 KB)
//   Emb   float[131072]  @ 1152K    (512 KB)  Emb[ch][pcol] = W_x[ch,oc]+b[oc]
//   hbuf  uint[2][4096*256] @ 1664K (8 MB)    ping-pong packed h (hi16|lo16)
//   barz  int[8224]      @ 10092544 (~33 KB)  [0]=generation, [32+b*32]=flag b
// ---------------------------------------------------------------------------

__global__ void pack_all(const float* __restrict__ W_lstm,
                         const float* __restrict__ b_lstm,
                         const float* __restrict__ W_dense,
                         unsigned short* __restrict__ Whi,
                         unsigned short* __restrict__ Wlo,
                         unsigned short* __restrict__ Wdhi,
                         unsigned short* __restrict__ Wdlo,
                         float* __restrict__ Emb,
                         int* __restrict__ barz) {
    int idx = blockIdx.x * blockDim.x + threadIdx.x;
    if (idx < 8224) barz[idx] = 0;
    if (idx < 262144) {
        // idx = (((cs*8+f)*8+kc)*64+lane)*8+j
        int j = idx & 7, lane = (idx >> 3) & 63, kc = (idx >> 9) & 7;
        int f = (idx >> 12) & 7, cs = idx >> 15;
        int oc = (f & 3) * 256 + cs * 32 + (f >> 2) * 16 + (lane & 15);
        int k  = kc * 32 + (lane >> 4) * 8 + j;
        float w = W_lstm[(size_t)(VCH + k) * GATES + oc];
        unsigned short hi = f2bf(w);
        Whi[idx] = hi;
        Wlo[idx] = f2bf(w - bf2f(hi));
    } else if (idx < 262144 + 32768) {
        int i2 = idx - 262144;
        int j = i2 & 7, lane = (i2 >> 3) & 63, kc = (i2 >> 9) & 7, f = i2 >> 12;
        int col = f * 16 + (lane & 15);
        int k   = kc * 32 + (lane >> 4) * 8 + j;
        float w = W_dense[(size_t)k * VCH + col];
        unsigned short hi = f2bf(w);
        Wdhi[i2] = hi;
        Wdlo[i2] = f2bf(w - bf2f(hi));
    } else if (idx < 262144 + 32768 + 131072) {
        int i3 = idx - (262144 + 32768);
        int pcol = i3 & 1023, ch = i3 >> 10;
        int cs = pcol >> 7, f = (pcol >> 4) & 7, n = pcol & 15;
        int oc = (f & 3) * 256 + cs * 32 + (f >> 2) * 16 + n;
        Emb[i3] = W_lstm[(size_t)ch * GATES + oc] + b_lstm[oc];
    }
}

// Flag-tree grid barrier, ZERO cache invalidates.
// Correctness: every wave's h stores (sc1) are drained by the vmcnt(0) the
// compiler emits before s_barrier (top __syncthreads) -> once a block's
// arrival flag (RELEASE) is visible, its h stores are at the L3 coherence
// point. Post-barrier h reads use sc1 loads -> no stale-cache hazard, so
// RELAXED polls suffice (no buffer_inv storm).
__device__ __forceinline__ void gridbar(int* __restrict__ barz, int want) {
    __syncthreads();
    if (blockIdx.x == 0) {
        int t = threadIdx.x;
        if (t > 0 && t < NBLK) {
            while (__hip_atomic_load(&barz[32 + t * 32], __ATOMIC_RELAXED,
                                     __HIP_MEMORY_SCOPE_AGENT) < want)
                __builtin_amdgcn_s_sleep(2);
        }
        __syncthreads();
        if (t == 0)
            __hip_atomic_store(&barz[0], want, __ATOMIC_RELEASE,
                               __HIP_MEMORY_SCOPE_AGENT);
        __syncthreads();
    } else {
        if (threadIdx.x == 0) {
            __hip_atomic_store(&barz[32 + blockIdx.x * 32], want, __ATOMIC_RELEASE,
                               __HIP_MEMORY_SCOPE_AGENT);
            while (__hip_atomic_load(&barz[0], __ATOMIC_RELAXED,
                                     __HIP_MEMORY_SCOPE_AGENT) < want)
                __builtin_amdgcn_s_sleep(2);
        }
        __syncthreads();
    }
}

__device__ __forceinline__ void unpack_a(uint4v u0, uint4v u1, short8& hi, short8& lo) {
    union { uint4v u; short8 s; } ch, cl;
    ch.u = (uint4v){ (u0[0] >> 16) | (u0[1] & 0xFFFF0000u),
                     (u0[2] >> 16) | (u0[3] & 0xFFFF0000u),
                     (u1[0] >> 16) | (u1[1] & 0xFFFF0000u),
                     (u1[2] >> 16) | (u1[3] & 0xFFFF0000u) };
    cl.u = (uint4v){ (u0[0] & 0xFFFFu) | (u0[1] << 16),
                     (u0[2] & 0xFFFFu) | (u0[3] << 16),
                     (u1[0] & 0xFFFFu) | (u1[1] << 16),
                     (u1[2] & 0xFFFFu) | (u1[3] << 16) };
    hi = ch.s;
    lo = cl.s;
}

__global__ __launch_bounds__(THREADS, 2)
void lstm_main(const int* __restrict__ inputs,
               const unsigned short* __restrict__ Whi,
               const unsigned short* __restrict__ Wlo,
               const unsigned short* __restrict__ Wdhi,
               const unsigned short* __restrict__ Wdlo,
               const float* __restrict__ Emb,
               const float* __restrict__ b_dense,
               unsigned int* __restrict__ hbuf,
               int* __restrict__ barz,
               float* __restrict__ out) {
    __shared__ __align__(16) unsigned short wsh[32768];   // 64 KB
    __shared__ __align__(16) unsigned short wsl[32768];   // 64 KB
    __shared__ int chs[SEQ * 128];                        // 20 KB

    const int tid  = threadIdx.x;
    const int lane = tid & 63;
    const int w    = tid >> 6;
    const int n    = lane & 15;
    const int kq   = lane >> 4;
    const int cs   = blockIdx.x >> 5;      // col-slice 0..7
    const int rg   = blockIdx.x & 31;      // row-group 0..31
    const int r0   = rg * 128;
    const int rw   = r0 + w * 16;

    // ---- stage weight slice into LDS (one-time) ---------------------------
    {
        const uint4v* gh = (const uint4v*)(Whi + (size_t)cs * 32768);
        const uint4v* gl = (const uint4v*)(Wlo + (size_t)cs * 32768);
        uint4v* lh = (uint4v*)wsh;
        uint4v* ll = (uint4v*)wsl;
        for (int i = tid; i < 4096; i += THREADS) { lh[i] = gh[i]; ll[i] = gl[i]; }
    }
    for (int i = tid; i < SEQ * 128; i += THREADS) {
        int row = i & 127, t = i >> 7;
        chs[t * 128 + row] = inputs[(size_t)(r0 + row) * SEQ + t];
    }
    for (int i = tid; i < 128 * 32; i += THREADS) {
        int rr = i >> 5, cc = i & 31;
        __hip_atomic_store(&hbuf[(size_t)(r0 + rr) * HID + cs * 32 + cc], 0u,
                           __ATOMIC_RELAXED, __HIP_MEMORY_SCOPE_AGENT);
    }

    float c_st[8];
#pragma unroll
    for (int i = 0; i < 8; ++i) c_st[i] = 0.0f;

    int gen = 1;
    gridbar(barz, gen); gen++;   // hbuf[0] zeros at L3; LDS staged

    const float* embbase = Emb + cs * 128 + n;

    // preload embedding gather for t=0 (plain cached loads; Emb is constant)
    float gv[8][4];
    {
        int ch[4];
#pragma unroll
        for (int r = 0; r < 4; ++r) ch[r] = chs[w * 16 + kq * 4 + r];
#pragma unroll
        for (int f = 0; f < 8; ++f)
#pragma unroll
            for (int r = 0; r < 4; ++r)
                gv[f][r] = embbase[(size_t)ch[r] * GATES + f * 16];
    }

#pragma unroll 1
    for (int t = 0; t < SEQ; ++t) {
        const unsigned int* hb = hbuf + (size_t)(t & 1) * 4096 * HID;
        unsigned int* hw = hbuf + (size_t)((t & 1) ^ 1) * 4096 * HID;

        // ---- A loads: 16x dwordx4 sc1 (L3-coherent), one drain ------------
        const unsigned int* arow = hb + (size_t)(rw + n) * HID + kq * 8;
        uint4v araw[16];
#pragma unroll
        for (int kc = 0; kc < 8; ++kc) {
            araw[kc * 2]     = ld16_sc1(arow + kc * 32);
            araw[kc * 2 + 1] = ld16_sc1(arow + kc * 32 + 4);
        }
        vm_drain();

        // ---- 3-pass MFMA: z = h @ W_slice ---------------------------------
        f32x4 acc[8];
#pragma unroll
        for (int f = 0; f < 8; ++f) acc[f] = (f32x4){0.f, 0.f, 0.f, 0.f};
#pragma unroll
        for (int kc = 0; kc < 8; ++kc) {
            short8 ahi, alo;
            unpack_a(araw[kc * 2], araw[kc * 2 + 1], ahi, alo);
#pragma unroll
            for (int f = 0; f < 8; ++f) {
                short8 bh = *(const short8*)&wsh[(f * 8 + kc) * 512 + lane * 8];
                short8 bl = *(const short8*)&wsl[(f * 8 + kc) * 512 + lane * 8];
                acc[f] = MFMA16(ahi, bh, acc[f]);
                acc[f] = MFMA16(alo, bh, acc[f]);
                acc[f] = MFMA16(ahi, bl, acc[f]);
            }
        }

        // ---- in-register cell update; publish h (sc1 stores) --------------
#pragma unroll
        for (int hf = 0; hf < 2; ++hf) {
#pragma unroll
            for (int r = 0; r < 4; ++r) {
                float zi = acc[hf * 4 + 0][r] + gv[hf * 4 + 0][r];
                float zj = acc[hf * 4 + 1][r] + gv[hf * 4 + 1][r];
                float zf = acc[hf * 4 + 2][r] + gv[hf * 4 + 2][r];
                float zo = acc[hf * 4 + 3][r] + gv[hf * 4 + 3][r];
                float cc = sigm(zf + 1.0f) * c_st[hf * 4 + r]
                         + sigm(zi) * tanh_fast(zj);
                c_st[hf * 4 + r] = cc;
                float hh = sigm(zo) * tanh_fast(cc);
                unsigned short hi = f2bf(hh);
                unsigned short lo = f2bf(hh - bf2f(hi));
                unsigned int pk = ((unsigned int)hi << 16) | (unsigned int)lo;
                __hip_atomic_store(&hw[(size_t)(rw + kq * 4 + r) * HID + cs * 32 + hf * 16 + n],
                                   pk, __ATOMIC_RELAXED, __HIP_MEMORY_SCOPE_AGENT);
            }
        }

        // ---- prefetch next step's embedding gather (cached; stays warm) ---
        if (t + 1 < SEQ) {
            int ch[4];
#pragma unroll
            for (int r = 0; r < 4; ++r) ch[r] = chs[(t + 1) * 128 + w * 16 + kq * 4 + r];
#pragma unroll
            for (int f = 0; f < 8; ++f)
#pragma unroll
                for (int r = 0; r < 4; ++r)
                    gv[f][r] = embbase[(size_t)ch[r] * GATES + f * 16];
        }

        gridbar(barz, gen); gen++;
    }

    // ---- final dense: out[:, cs*16..+16] = h @ Wd + b ---------------------
    {
        const unsigned int* arow = hbuf + (size_t)(rw + n) * HID + kq * 8;  // t=39 wrote buf[0]
        uint4v draw[16];
#pragma unroll
        for (int kc = 0; kc < 8; ++kc) {
            draw[kc * 2]     = ld16_sc1(arow + kc * 32);
            draw[kc * 2 + 1] = ld16_sc1(arow + kc * 32 + 4);
        }
        vm_drain();
        f32x4 dacc = (f32x4){0.f, 0.f, 0.f, 0.f};
#pragma unroll
        for (int kc = 0; kc < 8; ++kc) {
            short8 ahi, alo;
            unpack_a(draw[kc * 2], draw[kc * 2 + 1], ahi, alo);
            short8 bh = *(const short8*)(Wdhi + (size_t)(cs * 8 + kc) * 512 + lane * 8);
            short8 bl = *(const short8*)(Wdlo + (size_t)(cs * 8 + kc) * 512 + lane * 8);
            dacc = MFMA16(ahi, bh, dacc);
            dacc = MFMA16(alo, bh, dacc);
            dacc = MFMA16(ahi, bl, dacc);
        }
        float bd = b_dense[cs * 16 + n];
#pragma unroll
        for (int r = 0; r < 4; ++r) {
            out[(size_t)(rw + kq * 4 + r) * VCH + cs * 16 + n] = dacc[r] + bd;
        }
    }
}

extern "C" void kernel_launch(void* const* d_in, const int* in_sizes, int n_in,
                              void* d_out, int out_size, void* d_ws, size_t ws_size,
                              hipStream_t stream) {
    const int*   inputs  = (const int*)d_in[0];
    const float* W_lstm  = (const float*)d_in[1];
    const float* b_lstm  = (const float*)d_in[2];
    const float* W_dense = (const float*)d_in[3];
    const float* b_dense = (const float*)d_in[4];
    float* out = (float*)d_out;

    char* ws = (char*)d_ws;
    unsigned short* Whi  = (unsigned short*)(ws);
    unsigned short* Wlo  = (unsigned short*)(ws + 524288);
    unsigned short* Wdhi = (unsigned short*)(ws + 1048576);
    unsigned short* Wdlo = (unsigned short*)(ws + 1114112);
    float*          Emb  = (float*)(ws + 1179648);
    unsigned int*   hbuf = (unsigned int*)(ws + 1703936);
    int*            barz = (int*)(ws + 1703936 + 8388608);

    const int total = 262144 + 32768 + 131072;
    hipLaunchKernelGGL(pack_all, dim3((total + 255) / 256), dim3(256), 0, stream,
                       W_lstm, b_lstm, W_dense, Whi, Wlo, Wdhi, Wdlo, Emb, barz);

    void* args[] = { (void*)&inputs, (void*)&Whi, (void*)&Wlo, (void*)&Wdhi,
                     (void*)&Wdlo, (void*)&Emb, (void*)&b_dense, (void*)&hbuf,
                     (void*)&barz, (void*)&out };
    hipError_t err = hipLaunchCooperativeKernel((const void*)lstm_main, dim3(NBLK),
                                                dim3(THREADS), args, 0, stream);
    if (err != hipSuccess) {
        hipLaunchKernelGGL(lstm_main, dim3(NBLK), dim3(THREADS), 0, stream,
                           inputs, Whi, Wlo, Wdhi, Wdlo, Emb, b_dense, hbuf, barz, out);
    }
}

// Round 6
// 597.817 us; speedup vs baseline: 2.3370x; 1.0271x over previous
//
#include <hip/hip_runtime.h>

// Char-LSTM (B=4096, T=40, H=256, V=128) on MI355X — weight-stationary v4.
//
// R5 post-mortem: sc1 exchange killed the invalidate storm (1390->614us) but
// the 256-block leader-tree barrier remained: double L3 hop + 40x full-grid
// straggler coupling ~ 15us/step vs ~3us of work.
// R6 (single change): dependency graph is block-diagonal in row-group --
// block (cs,rg) only ever consumes h produced by {(cs',rg)}. Replace the grid
// barrier with 32 independent leaderless 8-block group barriers: each block
// release-stores its flag; threads 0..7 poll the group's 8 flags directly
// (one L3 hop, no leader round-trip); group members share one XCD (bid%8==rg%8).
// Exchange protocol (sc1 loads/stores, relaxed polls, monotonic generations,
// 2-buffer ping-pong) unchanged from R5 (validated: absmax 4.88e-4).

#define SEQ     40
#define VCH     128
#define HID     256
#define GATES   1024
#define NBLK    256
#define THREADS 512

typedef __attribute__((ext_vector_type(8))) short short8;   // 8 bf16
typedef __attribute__((ext_vector_type(4))) float f32x4;
typedef __attribute__((ext_vector_type(4))) unsigned int uint4v;

#define MFMA16(a, b, c) __builtin_amdgcn_mfma_f32_16x16x32_bf16((a), (b), (c), 0, 0, 0)

__device__ __forceinline__ unsigned short f2bf(float x) {
    unsigned u = __float_as_uint(x);
    return (unsigned short)((u + 0x7FFFu + ((u >> 16) & 1u)) >> 16);   // RNE
}
__device__ __forceinline__ float bf2f(unsigned short b) {
    return __uint_as_float(((unsigned)b) << 16);
}
__device__ __forceinline__ float sigm(float x) {
    return 1.0f / (1.0f + __expf(-x));
}
__device__ __forceinline__ float tanh_fast(float x) {
    float e = __expf(2.0f * x);
    return 1.0f - 2.0f / (e + 1.0f);
}

// 16B load bypassing L1/L2 (sc1): L3-coherent view, no invalidates needed.
// Result valid only after s_waitcnt vmcnt(0) + sched_barrier(0).
__device__ __forceinline__ uint4v ld16_sc1(const unsigned int* p) {
    uint4v r;
    asm volatile("global_load_dwordx4 %0, %1, off sc1"
                 : "=&v"(r) : "v"(p) : "memory");
    return r;
}
__device__ __forceinline__ void vm_drain() {
    asm volatile("s_waitcnt vmcnt(0)" ::: "memory");
    __builtin_amdgcn_sched_barrier(0);
}

// ---------------------------------------------------------------------------
// ws layout (bytes):
//   Whi   ushort[262144] @ 0        (512 KB)
//   Wlo   ushort[262144] @ 512K     (512 KB)
//   Wdhi  ushort[32768]  @ 1024K    ( 64 KB)
//   Wdlo  ushort[32768]  @ 1088K    ( 64 KB)
//   Emb   float[131072]  @ 1152K    (512 KB)  Emb[ch][pcol] = W_x[ch,oc]+b[oc]
//   hbuf  uint[2][4096*256] @ 1664K (8 MB)    ping-pong packed h (hi16|lo16)
//   barz  int[8224]      @ 10092544 (~33 KB)  [32+b*32] = arrival flag of block b
// ---------------------------------------------------------------------------

__global__ void pack_all(const float* __restrict__ W_lstm,
                         const float* __restrict__ b_lstm,
                         const float* __restrict__ W_dense,
                         unsigned short* __restrict__ Whi,
                         unsigned short* __restrict__ Wlo,
                         unsigned short* __restrict__ Wdhi,
                         unsigned short* __restrict__ Wdlo,
                         float* __restrict__ Emb,
                         int* __restrict__ barz) {
    int idx = blockIdx.x * blockDim.x + threadIdx.x;
    if (idx < 8224) barz[idx] = 0;
    if (idx < 262144) {
        // idx = (((cs*8+f)*8+kc)*64+lane)*8+j
        int j = idx & 7, lane = (idx >> 3) & 63, kc = (idx >> 9) & 7;
        int f = (idx >> 12) & 7, cs = idx >> 15;
        int oc = (f & 3) * 256 + cs * 32 + (f >> 2) * 16 + (lane & 15);
        int k  = kc * 32 + (lane >> 4) * 8 + j;
        float w = W_lstm[(size_t)(VCH + k) * GATES + oc];
        unsigned short hi = f2bf(w);
        Whi[idx] = hi;
        Wlo[idx] = f2bf(w - bf2f(hi));
    } else if (idx < 262144 + 32768) {
        int i2 = idx - 262144;
        int j = i2 & 7, lane = (i2 >> 3) & 63, kc = (i2 >> 9) & 7, f = i2 >> 12;
        int col = f * 16 + (lane & 15);
        int k   = kc * 32 + (lane >> 4) * 8 + j;
        float w = W_dense[(size_t)k * VCH + col];
        unsigned short hi = f2bf(w);
        Wdhi[i2] = hi;
        Wdlo[i2] = f2bf(w - bf2f(hi));
    } else if (idx < 262144 + 32768 + 131072) {
        int i3 = idx - (262144 + 32768);
        int pcol = i3 & 1023, ch = i3 >> 10;
        int cs = pcol >> 7, f = (pcol >> 4) & 7, n = pcol & 15;
        int oc = (f & 3) * 256 + cs * 32 + (f >> 2) * 16 + n;
        Emb[i3] = W_lstm[(size_t)ch * GATES + oc] + b_lstm[oc];
    }
}

// Leaderless 8-block group barrier (blocks {c*32+rg, c=0..7}), zero invalidates.
// Top __syncthreads: every wave drains vmem (compiler emits vmcnt(0) before
// s_barrier) -> this block's sc1 h stores are at L3 before the flag release.
// Threads 0..7 poll the group's 8 flags directly (RELAXED, single L3 hop);
// post-barrier h reads are sc1 so no stale-cache hazard exists.
__device__ __forceinline__ void groupbar(int* __restrict__ barz, int rg, int want) {
    __syncthreads();
    if (threadIdx.x == 0)
        __hip_atomic_store(&barz[32 + blockIdx.x * 32], want, __ATOMIC_RELEASE,
                           __HIP_MEMORY_SCOPE_AGENT);
    if (threadIdx.x < 8) {
        while (__hip_atomic_load(&barz[32 + (threadIdx.x * 32 + rg) * 32],
                                 __ATOMIC_RELAXED, __HIP_MEMORY_SCOPE_AGENT) < want)
            __builtin_amdgcn_s_sleep(1);
    }
    __syncthreads();
}

__device__ __forceinline__ void unpack_a(uint4v u0, uint4v u1, short8& hi, short8& lo) {
    union { uint4v u; short8 s; } ch, cl;
    ch.u = (uint4v){ (u0[0] >> 16) | (u0[1] & 0xFFFF0000u),
                     (u0[2] >> 16) | (u0[3] & 0xFFFF0000u),
                     (u1[0] >> 16) | (u1[1] & 0xFFFF0000u),
                     (u1[2] >> 16) | (u1[3] & 0xFFFF0000u) };
    cl.u = (uint4v){ (u0[0] & 0xFFFFu) | (u0[1] << 16),
                     (u0[2] & 0xFFFFu) | (u0[3] << 16),
                     (u1[0] & 0xFFFFu) | (u1[1] << 16),
                     (u1[2] & 0xFFFFu) | (u1[3] << 16) };
    hi = ch.s;
    lo = cl.s;
}

__global__ __launch_bounds__(THREADS, 2)
void lstm_main(const int* __restrict__ inputs,
               const unsigned short* __restrict__ Whi,
               const unsigned short* __restrict__ Wlo,
               const unsigned short* __restrict__ Wdhi,
               const unsigned short* __restrict__ Wdlo,
               const float* __restrict__ Emb,
               const float* __restrict__ b_dense,
               unsigned int* __restrict__ hbuf,
               int* __restrict__ barz,
               float* __restrict__ out) {
    __shared__ __align__(16) unsigned short wsh[32768];   // 64 KB
    __shared__ __align__(16) unsigned short wsl[32768];   // 64 KB
    __shared__ int chs[SEQ * 128];                        // 20 KB

    const int tid  = threadIdx.x;
    const int lane = tid & 63;
    const int w    = tid >> 6;
    const int n    = lane & 15;
    const int kq   = lane >> 4;
    const int cs   = blockIdx.x >> 5;      // col-slice 0..7
    const int rg   = blockIdx.x & 31;      // row-group 0..31 (group id)
    const int r0   = rg * 128;
    const int rw   = r0 + w * 16;

    // ---- stage weight slice into LDS (one-time) ---------------------------
    {
        const uint4v* gh = (const uint4v*)(Whi + (size_t)cs * 32768);
        const uint4v* gl = (const uint4v*)(Wlo + (size_t)cs * 32768);
        uint4v* lh = (uint4v*)wsh;
        uint4v* ll = (uint4v*)wsl;
        for (int i = tid; i < 4096; i += THREADS) { lh[i] = gh[i]; ll[i] = gl[i]; }
    }
    for (int i = tid; i < SEQ * 128; i += THREADS) {
        int row = i & 127, t = i >> 7;
        chs[t * 128 + row] = inputs[(size_t)(r0 + row) * SEQ + t];
    }
    for (int i = tid; i < 128 * 32; i += THREADS) {
        int rr = i >> 5, cc = i & 31;
        __hip_atomic_store(&hbuf[(size_t)(r0 + rr) * HID + cs * 32 + cc], 0u,
                           __ATOMIC_RELAXED, __HIP_MEMORY_SCOPE_AGENT);
    }

    float c_st[8];
#pragma unroll
    for (int i = 0; i < 8; ++i) c_st[i] = 0.0f;

    int gen = 1;
    groupbar(barz, rg, gen); gen++;   // group's hbuf[0] zeros at L3; LDS staged

    const float* embbase = Emb + cs * 128 + n;

    // preload embedding gather for t=0 (cached loads; Emb constant)
    float gv[8][4];
    {
        int ch[4];
#pragma unroll
        for (int r = 0; r < 4; ++r) ch[r] = chs[w * 16 + kq * 4 + r];
#pragma unroll
        for (int f = 0; f < 8; ++f)
#pragma unroll
            for (int r = 0; r < 4; ++r)
                gv[f][r] = embbase[(size_t)ch[r] * GATES + f * 16];
    }

#pragma unroll 1
    for (int t = 0; t < SEQ; ++t) {
        const unsigned int* hb = hbuf + (size_t)(t & 1) * 4096 * HID;
        unsigned int* hw = hbuf + (size_t)((t & 1) ^ 1) * 4096 * HID;

        // ---- A loads: 16x dwordx4 sc1 (L3-coherent), one drain ------------
        const unsigned int* arow = hb + (size_t)(rw + n) * HID + kq * 8;
        uint4v araw[16];
#pragma unroll
        for (int kc = 0; kc < 8; ++kc) {
            araw[kc * 2]     = ld16_sc1(arow + kc * 32);
            araw[kc * 2 + 1] = ld16_sc1(arow + kc * 32 + 4);
        }
        vm_drain();

        // ---- 3-pass MFMA: z = h @ W_slice ---------------------------------
        f32x4 acc[8];
#pragma unroll
        for (int f = 0; f < 8; ++f) acc[f] = (f32x4){0.f, 0.f, 0.f, 0.f};
#pragma unroll
        for (int kc = 0; kc < 8; ++kc) {
            short8 ahi, alo;
            unpack_a(araw[kc * 2], araw[kc * 2 + 1], ahi, alo);
#pragma unroll
            for (int f = 0; f < 8; ++f) {
                short8 bh = *(const short8*)&wsh[(f * 8 + kc) * 512 + lane * 8];
                short8 bl = *(const short8*)&wsl[(f * 8 + kc) * 512 + lane * 8];
                acc[f] = MFMA16(ahi, bh, acc[f]);
                acc[f] = MFMA16(alo, bh, acc[f]);
                acc[f] = MFMA16(ahi, bl, acc[f]);
            }
        }

        // ---- in-register cell update; publish h (sc1 stores) --------------
#pragma unroll
        for (int hf = 0; hf < 2; ++hf) {
#pragma unroll
            for (int r = 0; r < 4; ++r) {
                float zi = acc[hf * 4 + 0][r] + gv[hf * 4 + 0][r];
                float zj = acc[hf * 4 + 1][r] + gv[hf * 4 + 1][r];
                float zf = acc[hf * 4 + 2][r] + gv[hf * 4 + 2][r];
                float zo = acc[hf * 4 + 3][r] + gv[hf * 4 + 3][r];
                float cc = sigm(zf + 1.0f) * c_st[hf * 4 + r]
                         + sigm(zi) * tanh_fast(zj);
                c_st[hf * 4 + r] = cc;
                float hh = sigm(zo) * tanh_fast(cc);
                unsigned short hi = f2bf(hh);
                unsigned short lo = f2bf(hh - bf2f(hi));
                unsigned int pk = ((unsigned int)hi << 16) | (unsigned int)lo;
                __hip_atomic_store(&hw[(size_t)(rw + kq * 4 + r) * HID + cs * 32 + hf * 16 + n],
                                   pk, __ATOMIC_RELAXED, __HIP_MEMORY_SCOPE_AGENT);
            }
        }

        // ---- prefetch next step's embedding gather (cached; stays warm) ---
        if (t + 1 < SEQ) {
            int ch[4];
#pragma unroll
            for (int r = 0; r < 4; ++r) ch[r] = chs[(t + 1) * 128 + w * 16 + kq * 4 + r];
#pragma unroll
            for (int f = 0; f < 8; ++f)
#pragma unroll
                for (int r = 0; r < 4; ++r)
                    gv[f][r] = embbase[(size_t)ch[r] * GATES + f * 16];
        }

        groupbar(barz, rg, gen); gen++;
    }

    // ---- final dense: out[:, cs*16..+16] = h @ Wd + b ---------------------
    {
        const unsigned int* arow = hbuf + (size_t)(rw + n) * HID + kq * 8;  // t=39 wrote buf[0]
        uint4v draw[16];
#pragma unroll
        for (int kc = 0; kc < 8; ++kc) {
            draw[kc * 2]     = ld16_sc1(arow + kc * 32);
            draw[kc * 2 + 1] = ld16_sc1(arow + kc * 32 + 4);
        }
        vm_drain();
        f32x4 dacc = (f32x4){0.f, 0.f, 0.f, 0.f};
#pragma unroll
        for (int kc = 0; kc < 8; ++kc) {
            short8 ahi, alo;
            unpack_a(draw[kc * 2], draw[kc * 2 + 1], ahi, alo);
            short8 bh = *(const short8*)(Wdhi + (size_t)(cs * 8 + kc) * 512 + lane * 8);
            short8 bl = *(const short8*)(Wdlo + (size_t)(cs * 8 + kc) * 512 + lane * 8);
            dacc = MFMA16(ahi, bh, dacc);
            dacc = MFMA16(alo, bh, dacc);
            dacc = MFMA16(ahi, bl, dacc);
        }
        float bd = b_dense[cs * 16 + n];
#pragma unroll
        for (int r = 0; r < 4; ++r) {
            out[(size_t)(rw + kq * 4 + r) * VCH + cs * 16 + n] = dacc[r] + bd;
        }
    }
}

extern "C" void kernel_launch(void* const* d_in, const int* in_sizes, int n_in,
                              void* d_out, int out_size, void* d_ws, size_t ws_size,
                              hipStream_t stream) {
    const int*   inputs  = (const int*)d_in[0];
    const float* W_lstm  = (const float*)d_in[1];
    const float* b_lstm  = (const float*)d_in[2];
    const float* W_dense = (const float*)d_in[3];
    const float* b_dense = (const float*)d_in[4];
    float* out = (float*)d_out;

    char* ws = (char*)d_ws;
    unsigned short* Whi  = (unsigned short*)(ws);
    unsigned short* Wlo  = (unsigned short*)(ws + 524288);
    unsigned short* Wdhi = (unsigned short*)(ws + 1048576);
    unsigned short* Wdlo = (unsigned short*)(ws + 1114112);
    float*          Emb  = (float*)(ws + 1179648);
    unsigned int*   hbuf = (unsigned int*)(ws + 1703936);
    int*            barz = (int*)(ws + 1703936 + 8388608);

    const int total = 262144 + 32768 + 131072;
    hipLaunchKernelGGL(pack_all, dim3((total + 255) / 256), dim3(256), 0, stream,
                       W_lstm, b_lstm, W_dense, Whi, Wlo, Wdhi, Wdlo, Emb, barz);

    void* args[] = { (void*)&inputs, (void*)&Whi, (void*)&Wlo, (void*)&Wdhi,
                     (void*)&Wdlo, (void*)&Emb, (void*)&b_dense, (void*)&hbuf,
                     (void*)&barz, (void*)&out };
    hipError_t err = hipLaunchCooperativeKernel((const void*)lstm_main, dim3(NBLK),
                                                dim3(THREADS), args, 0, stream);
    if (err != hipSuccess) {
        hipLaunchKernelGGL(lstm_main, dim3(NBLK), dim3(THREADS), 0, stream,
                           inputs, Whi, Wlo, Wdhi, Wdlo, Emb, b_dense, hbuf, barz, out);
    }
}